// Round 16
// baseline (267.616 us; speedup 1.0000x reference)
//
#include <hip/hip_runtime.h>
#include <hip/hip_bf16.h>

// Problem constants
#define BB 8
#define SS 2048
#define DD 256
#define HH 512
#define LL 3
#define NROWS (BB * SS)

typedef float floatx4 __attribute__((ext_vector_type(4)));

// ---------------------------------------------------------------------------
// A/mask row worker (NT stores; verified R10). tid-parametrized for use from
// 512-thread blocks (two 256-thread subgroups).
// ---------------------------------------------------------------------------
__device__ __forceinline__ void amask_row(const float* __restrict__ psi,
                                          float* __restrict__ A, float* __restrict__ M,
                                          int blk, int tid)
{
    int b = blk >> 11, i = blk & (SS - 1);
    float2 pi = *reinterpret_cast<const float2*>(psi + (size_t)blk * 2);
    #pragma unroll
    for (int c = 0; c < 2; ++c) {
        int j0 = c * 1024 + tid * 4;
        const float4* pr = reinterpret_cast<const float4*>(psi + ((size_t)b * SS + j0) * 2);
        float4 q0 = pr[0], q1 = pr[1];
        floatx4 o;
        o.x = pi.x * q0.x + pi.y * q0.y;
        o.y = pi.x * q0.z + pi.y * q0.w;
        o.z = pi.x * q1.x + pi.y * q1.y;
        o.w = pi.x * q1.z + pi.y * q1.w;
        size_t rb = (size_t)blk * SS + j0;
        __builtin_nontemporal_store(o, reinterpret_cast<floatx4*>(A + rb));
        floatx4 m;
        m.x = (i == j0    ) ? 1.f : 0.f;
        m.y = (i == j0 + 1) ? 1.f : 0.f;
        m.z = (i == j0 + 2) ? 1.f : 0.f;
        m.w = (i == j0 + 3) ? 1.f : 0.f;
        __builtin_nontemporal_store(m, reinterpret_cast<floatx4*>(M + rb));
    }
}

// ---------------------------------------------------------------------------
// Launch 1: per-block M in LDS -> psi (16 rows/block) + h0 (verified R13)
// ---------------------------------------------------------------------------
__global__ void psiM_kernel(const float* __restrict__ x,
                            const float* __restrict__ pw, const float* __restrict__ pb,
                            const float* __restrict__ pe, const float* __restrict__ hebb,
                            float* __restrict__ psi, float* __restrict__ Tbase)
{
    __shared__ __align__(16) float sM[516];
    const int tid = threadIdx.x;
    const int bid = blockIdx.x;

    {   // M[k][t] for k=tid; coalesced pw reads, broadcast pe
        float a0 = 0.f, a1 = 0.f;
        for (int d = 0; d < DD; ++d) {
            float w = pw[d * DD + tid];
            a0 += w * pe[2 * d];
            a1 += w * pe[2 * d + 1];
        }
        sM[2 * tid] = a0;
        sM[2 * tid + 1] = a1;
    }
    if (tid < 64) {
        float c0 = 0.f, c1 = 0.f;
        for (int d = tid; d < DD; d += 64) {
            c0 += pb[d] * pe[2 * d];
            c1 += pb[d] * pe[2 * d + 1];
        }
        #pragma unroll
        for (int dd = 32; dd; dd >>= 1) {
            c0 += __shfl_xor(c0, dd);
            c1 += __shfl_xor(c1, dd);
        }
        if (tid == 0) { sM[512] = c0; sM[513] = c1; }
    }
    __syncthreads();

    int wave = tid >> 6, lane = tid & 63;
    const float4* sM4 = reinterpret_cast<const float4*>(sM);
    float4 mA = sM4[lane * 2];
    float4 mB = sM4[lane * 2 + 1];
    float c0 = sM[512], c1 = sM[513];
    int base = bid * 16 + wave * 4;
    #pragma unroll
    for (int it = 0; it < 4; ++it) {
        int rid = base + it;
        float4 v = *reinterpret_cast<const float4*>(x + (size_t)rid * DD + lane * 4);
        float a0 = v.x * mA.x + v.y * mA.z + v.z * mB.x + v.w * mB.z;
        float a1 = v.x * mA.y + v.y * mA.w + v.z * mB.y + v.w * mB.w;
        #pragma unroll
        for (int d = 32; d; d >>= 1) {
            a0 += __shfl_xor(a0, d);
            a1 += __shfl_xor(a1, d);
        }
        a0 += c0;
        a1 += c1;
        float n = sqrtf(a0 * a0 + a1 * a1);
        float scale = 1.f / (n + 1e-8f);
        float r = n * scale;
        #pragma unroll
        for (int i7 = 0; i7 < 7; ++i7) {
            float f = r / (r + 1e-8f);
            scale *= f;
            r *= f;
        }
        float px = a0 * scale, py = a1 * scale;
        if (lane == 0) {
            float2 pv;
            pv.x = px;
            pv.y = py;
            *reinterpret_cast<float2*>(psi + (size_t)rid * 2) = pv;
        }
        if ((rid & (SS - 1)) == SS - 1) {   // h0 -> Tbase
            int b = rid >> 11;
            for (int j = lane; j < HH; j += 64)
                Tbase[(size_t)b * HH + j] = px * hebb[2 * j] + py * hebb[2 * j + 1];
        }
    }
}

// ---------------------------------------------------------------------------
// VO carrier: fused t1 = X0 + (X0 @ Wv^T + bv) @ Wo^T + bo, X0 = LN?(T).
// 64 mm blocks x 512 threads: full v[8][512] per block (redundant, 1 j/thread,
// 8 waves, high load ILP), then 8-wide o slice per block (64-lane reduce).
// Blocks >= 64: A/mask stores, 2 rows each (256-thread subgroups).
// ---------------------------------------------------------------------------
__global__ void __launch_bounds__(512) vo_carrier(
    const float* __restrict__ T,
    const float* __restrict__ pxw, const float* __restrict__ pxb,
    const float* __restrict__ Wv, const float* __restrict__ bv,
    const float* __restrict__ Wo, const float* __restrict__ bo,
    float* __restrict__ T1,
    const float* __restrict__ psi, float* __restrict__ A, float* __restrict__ Mask,
    int arow0)
{
    const int bid = blockIdx.x;
    const int tid = threadIdx.x;
    if (bid >= 64) {
        int r = arow0 + (bid - 64) * 2 + (tid >> 8);
        if (r < NROWS) amask_row(psi, A, Mask, r, tid & 255);
        return;
    }

    __shared__ __align__(16) float sX0[8 * HH];
    __shared__ __align__(16) float sV[8 * HH];
    __shared__ float s_m[8], s_r[8];

    // X0 = LN?(T) (8 rows; 64 lanes per row for stats)
    if (pxw) {
        int row = tid >> 6, lane = tid & 63;
        float s = 0.f, ss = 0.f;
        for (int k = lane; k < HH; k += 64) {
            float v = T[row * HH + k];
            s += v; ss += v * v;
        }
        #pragma unroll
        for (int d = 32; d; d >>= 1) {
            s += __shfl_xor(s, d);
            ss += __shfl_xor(ss, d);
        }
        if (lane == 0) {
            float m = s / HH;
            s_m[row] = m;
            s_r[row] = rsqrtf(ss / HH - m * m + 1e-5f);
        }
        __syncthreads();
        for (int idx = tid; idx < 8 * HH; idx += 512) {
            int b = idx >> 9, k = idx & 511;
            sX0[idx] = (T[idx] - s_m[b]) * s_r[b] * pxw[k] + pxb[k];
        }
    } else {
        for (int idx = tid; idx < 8 * HH; idx += 512) sX0[idx] = T[idx];
    }
    __syncthreads();

    // full v: one j per thread
    {
        int j = tid;
        const float4* Wv4 = reinterpret_cast<const float4*>(Wv + (size_t)j * HH);
        const float4* X4 = reinterpret_cast<const float4*>(sX0);
        float acc[8] = {0.f, 0.f, 0.f, 0.f, 0.f, 0.f, 0.f, 0.f};
        for (int i4 = 0; i4 < 128; ++i4) {
            float4 w = Wv4[i4];
            #pragma unroll
            for (int b = 0; b < 8; ++b) {
                float4 xv = X4[b * 128 + i4];   // broadcast across lanes
                acc[b] = fmaf(w.x, xv.x, acc[b]);
                acc[b] = fmaf(w.y, xv.y, acc[b]);
                acc[b] = fmaf(w.z, xv.z, acc[b]);
                acc[b] = fmaf(w.w, xv.w, acc[b]);
            }
        }
        float bvj = bv[j];
        #pragma unroll
        for (int b = 0; b < 8; ++b) sV[b * HH + j] = acc[b] + bvj;
    }
    __syncthreads();

    // o slice: j = bid*8 + (tid>>6), 64 lanes per j (2 float4 each)
    {
        int r = tid >> 6, lane = tid & 63;
        int j = bid * 8 + r;
        const float4* Wo4 = reinterpret_cast<const float4*>(Wo + (size_t)j * HH);
        const float4* V4 = reinterpret_cast<const float4*>(sV);
        float acc[8] = {0.f, 0.f, 0.f, 0.f, 0.f, 0.f, 0.f, 0.f};
        #pragma unroll
        for (int h = 0; h < 2; ++h) {
            int i4 = lane + h * 64;
            float4 w = Wo4[i4];
            #pragma unroll
            for (int b = 0; b < 8; ++b) {
                float4 vv = V4[b * 128 + i4];
                acc[b] = fmaf(w.x, vv.x, acc[b]);
                acc[b] = fmaf(w.y, vv.y, acc[b]);
                acc[b] = fmaf(w.z, vv.z, acc[b]);
                acc[b] = fmaf(w.w, vv.w, acc[b]);
            }
        }
        #pragma unroll
        for (int d = 32; d; d >>= 1) {
            #pragma unroll
            for (int b = 0; b < 8; ++b) acc[b] += __shfl_down(acc[b], d);
        }
        if (lane == 0) {
            float boj = bo[j];
            #pragma unroll
            for (int b = 0; b < 8; ++b)
                T1[(size_t)b * HH + j] = sX0[b * HH + j] + acc[b] + boj;
        }
    }
}

// ---------------------------------------------------------------------------
// Generic tiny-batch GEMM carrier (verified R10/R14), + moonlighted stores.
// ---------------------------------------------------------------------------
__global__ void head_mm(const float* __restrict__ X, int K,
                        const float* __restrict__ xlnw, const float* __restrict__ xlnb,
                        const float* __restrict__ W, const float* __restrict__ bias,
                        const float* __restrict__ res,
                        const float* __restrict__ reslnw, const float* __restrict__ reslnb,
                        float* __restrict__ out, int J, int G, int act,
                        const float* __restrict__ psi,
                        float* __restrict__ Ao, float* __restrict__ Mo,
                        int mmBlocks, int arow0)
{
    const int bid = blockIdx.x;
    if (bid >= mmBlocks) {
        int r = arow0 + (bid - mmBlocks);
        if (r < NROWS) amask_row(psi, Ao, Mo, r, threadIdx.x);
        return;
    }

    extern __shared__ float sX[];
    __shared__ float s_m[8], s_r[8], s_rm[8], s_rr[8];
    const int tid = threadIdx.x;
    const int row = tid >> 5, lane = tid & 31;
    const bool doLN = (xlnw != nullptr);
    const bool doRLN = (res != nullptr) && (reslnw != nullptr);

    if (doLN) {
        float s = 0.f, ss = 0.f;
        for (int k = lane; k < K; k += 32) {
            float v = X[row * K + k];
            s += v; ss += v * v;
        }
        for (int d = 16; d; d >>= 1) { s += __shfl_down(s, d); ss += __shfl_down(ss, d); }
        if (lane == 0) {
            float m = s / K;
            s_m[row] = m;
            s_r[row] = rsqrtf(ss / K - m * m + 1e-5f);
        }
    }
    if (doRLN) {
        float s = 0.f, ss = 0.f;
        for (int k = lane; k < J; k += 32) {
            float v = res[row * J + k];
            s += v; ss += v * v;
        }
        for (int d = 16; d; d >>= 1) { s += __shfl_down(s, d); ss += __shfl_down(ss, d); }
        if (lane == 0) {
            float m = s / J;
            s_rm[row] = m;
            s_rr[row] = rsqrtf(ss / J - m * m + 1e-5f);
        }
    }
    __syncthreads();

    if (doLN) {
        for (int idx = tid; idx < 8 * K; idx += 256) {
            int b = idx / K, k = idx - b * K;
            sX[idx] = (X[idx] - s_m[b]) * s_r[b] * xlnw[k] + xlnb[k];
        }
        __syncthreads();
    }

    const float* __restrict__ Xp = doLN ? (const float*)sX : X;
    const int g = tid & (G - 1);
    const int jj = tid / G;
    const int j = bid * (256 / G) + jj;

    float acc[8] = {0.f, 0.f, 0.f, 0.f, 0.f, 0.f, 0.f, 0.f};
    if (j < J) {
        const float4* W4 = reinterpret_cast<const float4*>(W + (size_t)j * K);
        const int K4 = K >> 2;
        for (int i4 = g; i4 < K4; i4 += G) {
            float4 w4 = W4[i4];
            int k = i4 << 2;
            #pragma unroll
            for (int b = 0; b < 8; ++b) {
                float4 xv = *reinterpret_cast<const float4*>(Xp + b * K + k);
                acc[b] = fmaf(w4.x, xv.x, acc[b]);
                acc[b] = fmaf(w4.y, xv.y, acc[b]);
                acc[b] = fmaf(w4.z, xv.z, acc[b]);
                acc[b] = fmaf(w4.w, xv.w, acc[b]);
            }
        }
    }
    for (int d = G >> 1; d; d >>= 1) {
        #pragma unroll
        for (int b = 0; b < 8; ++b) acc[b] += __shfl_down(acc[b], d);
    }
    if (g == 0 && j < J) {
        float bs = bias ? bias[j] : 0.f;
        #pragma unroll
        for (int b = 0; b < 8; ++b) {
            float v = acc[b] + bs;
            if (act) v = v / (1.f + expf(-v));   // silu
            if (res) {
                float rv = res[(size_t)b * J + j];
                if (reslnw) rv = (rv - s_rm[b]) * s_rr[b] * reslnw[j] + reslnb[j];
                v += rv;
            }
            out[(size_t)b * J + j] = v;
        }
    }
}

// ---------------------------------------------------------------------------
// Per-row LN for [8][N] in LDS (verified R13/R14). sh=log2(N). In-place safe.
// ---------------------------------------------------------------------------
__device__ __forceinline__ void ln8(const float* in, float* out, int N, int sh,
                                    const float* __restrict__ w,
                                    const float* __restrict__ bvec,
                                    float* s_m, float* s_r, int tid)
{
    int row = tid >> 5, lane = tid & 31;
    float s = 0.f, ss = 0.f;
    for (int k = lane; k < N; k += 32) {
        float v = in[(row << sh) + k];
        s += v; ss += v * v;
    }
    #pragma unroll
    for (int d = 16; d; d >>= 1) { s += __shfl_down(s, d); ss += __shfl_down(ss, d); }
    if (lane == 0) {
        float m = s / N;
        s_m[row] = m;
        s_r[row] = rsqrtf(ss / N - m * m + 1e-5f);
    }
    __syncthreads();
    for (int idx = tid; idx < (N << 3); idx += 256) {
        int b = idx >> sh, k = idx & (N - 1);
        out[idx] = (in[idx] - s_m[b]) * s_r[b] * w[k] + bvec[k];
    }
    __syncthreads();
}

// ---------------------------------------------------------------------------
// Tail carrier (verified R14): block 0 = LN chain + p1/silu + LN + preds;
// blocks >= 1 stream A/mask rows.
// ---------------------------------------------------------------------------
__global__ void tail_kernel(const float* __restrict__ T,
                            const float* __restrict__ ln2w, const float* __restrict__ ln2b,
                            const float* __restrict__ nAw, const float* __restrict__ nAb,
                            const float* __restrict__ nBw, const float* __restrict__ nBb,
                            const float* __restrict__ p1w, const float* __restrict__ p1b,
                            const float* __restrict__ p2w, const float* __restrict__ p2b,
                            float* __restrict__ preds,
                            const float* __restrict__ psi,
                            float* __restrict__ Ao, float* __restrict__ Mo, int arow0)
{
    const int bid = blockIdx.x;
    const int tid = threadIdx.x;
    if (bid >= 1) {
        int r = arow0 + (bid - 1);
        if (r < NROWS) amask_row(psi, Ao, Mo, r, tid);
        return;
    }
    __shared__ __align__(16) float sT[8 * HH];
    __shared__ __align__(16) float sX[8 * HH];
    __shared__ __align__(16) float sS[8 * 256];
    __shared__ float s_m[8], s_r[8];
    const float4* sX4 = reinterpret_cast<const float4*>(sX);

    for (int idx = tid; idx < 4096; idx += 256) sT[idx] = T[idx];
    __syncthreads();
    ln8(sT, sX, HH, 9, ln2w + 2 * HH, ln2b + 2 * HH, s_m, s_r, tid);
    ln8(sX, sX, HH, 9, nAw, nAb, s_m, s_r, tid);
    {
        int j = tid;
        float acc[8] = {0,0,0,0,0,0,0,0};
        const float4* W4 = reinterpret_cast<const float4*>(p1w + (size_t)j * HH);
        for (int i4 = 0; i4 < 128; ++i4) {
            float4 w = W4[i4];
            #pragma unroll
            for (int b = 0; b < 8; ++b) {
                float4 xv = sX4[b * 128 + i4];
                acc[b] = fmaf(w.x, xv.x, acc[b]);
                acc[b] = fmaf(w.y, xv.y, acc[b]);
                acc[b] = fmaf(w.z, xv.z, acc[b]);
                acc[b] = fmaf(w.w, xv.w, acc[b]);
            }
        }
        float bp = p1b[j];
        #pragma unroll
        for (int b = 0; b < 8; ++b) {
            float v = acc[b] + bp;
            v = v / (1.f + expf(-v));
            sS[b * 256 + j] = v;
        }
    }
    __syncthreads();
    ln8(sS, sS, 256, 8, nBw, nBb, s_m, s_r, tid);
    {
        int b = tid >> 5, k = tid & 31;
        float s = 0.f;
        for (int kk = k; kk < 256; kk += 32) s += sS[b * 256 + kk] * p2w[kk];
        #pragma unroll
        for (int d = 16; d; d >>= 1) s += __shfl_down(s, d);
        if (k == 0) preds[b] = s + p2b[0];
    }
}

// ---------------------------------------------------------------------------
extern "C" void kernel_launch(void* const* d_in, const int* in_sizes, int n_in,
                              void* d_out, int out_size, void* d_ws, size_t ws_size,
                              hipStream_t stream)
{
    const float* x      = (const float*)d_in[0];
    const float* proj_w = (const float*)d_in[1];
    const float* proj_b = (const float*)d_in[2];
    const float* pe     = (const float*)d_in[3];
    const float* hebb   = (const float*)d_in[4];
    const float* ai_w   = (const float*)d_in[5];
    const float* ai_b   = (const float*)d_in[6];
    const float* ao_w   = (const float*)d_in[7];
    const float* ao_b   = (const float*)d_in[8];
    const float* f1_w   = (const float*)d_in[9];
    const float* f1_b   = (const float*)d_in[10];
    const float* f2_w   = (const float*)d_in[11];
    const float* f2_b   = (const float*)d_in[12];
    const float* ln1w   = (const float*)d_in[13];
    const float* ln1b   = (const float*)d_in[14];
    const float* ln2w   = (const float*)d_in[15];
    const float* ln2b   = (const float*)d_in[16];
    const float* nAw    = (const float*)d_in[17];
    const float* nAb    = (const float*)d_in[18];
    const float* nBw    = (const float*)d_in[19];
    const float* nBb    = (const float*)d_in[20];
    const float* p1w    = (const float*)d_in[21];
    const float* p1b    = (const float*)d_in[22];
    const float* p2w    = (const float*)d_in[23];
    const float* p2b    = (const float*)d_in[24];

    float* out   = (float*)d_out;
    // output layout: preds(8) | A(B*S*S) | mask(B*S*S) | psi(B*S*2)
    float* preds = out;
    float* A     = out + 8;
    float* Mask  = out + 8 + (size_t)BB * SS * SS;
    float* Psi   = out + 8 + (size_t)2 * BB * SS * SS;

    float* ws = (float*)d_ws;
    float* T  = ws + 640;      // 8x512
    float* T1 = ws + 8832;     // 8x512
    float* F  = ws + 12928;    // 8x2048

    // ---- Launch 1: psi + h0 (per-block M recompute) ----
    psiM_kernel<<<NROWS / 16, 256, 0, stream>>>(x, proj_w, proj_b, pe, hebb, Psi, T);

    // ---- 9 layer carriers + tail; stores moonlighted ----
    int arow = 0;
    const int QROW = 1638;     // 9 x 1638 = 14742; tail covers 1642
    for (int l = 0; l < LL; ++l) {
        const float* pxw = l ? ln2w + (l - 1) * HH : nullptr;
        const float* pxb = l ? ln2b + (l - 1) * HH : nullptr;
        // t1 = X0 + (X0@Wv^T+bv)@Wo^T + bo   (fused; 64 mm blocks x 512 thr)
        vo_carrier<<<64 + QROW / 2, 512, 0, stream>>>(
            T, pxw, pxb,
            ai_w + ((size_t)l * 3 * HH + 2 * HH) * HH, ai_b + l * 3 * HH + 2 * HH,
            ao_w + (size_t)l * HH * HH, ao_b + l * HH,
            T1, Psi, A, Mask, arow);
        arow += QROW;
        // f = silu(LN(t1,ln1) @ W1^T + b1)   (J=2048, K=512, G=16)
        head_mm<<<128 + QROW, 256, 8 * HH * 4, stream>>>(
            T1, HH, ln1w + l * HH, ln1b + l * HH,
            f1_w + (size_t)l * 4 * HH * HH, f1_b + l * 4 * HH,
            nullptr, nullptr, nullptr, F, 4 * HH, 16, 1,
            Psi, A, Mask, 128, arow);
        arow += QROW;
        // t2 = LN(t1,ln1) + (f @ W2^T + b2)  (J=512, K=2048, G=64)
        head_mm<<<128 + QROW, 256, 0, stream>>>(
            F, 4 * HH, nullptr, nullptr,
            f2_w + (size_t)l * HH * 4 * HH, f2_b + l * HH,
            T1, ln1w + l * HH, ln1b + l * HH, T, HH, 64, 0,
            Psi, A, Mask, 128, arow);
        arow += QROW;
    }
    // ---- tail: LN chain + p1 + preds (block 0) + remaining store rows ----
    {
        int qrem = NROWS - arow;   // 1642
        tail_kernel<<<1 + qrem, 256, 0, stream>>>(
            T, ln2w, ln2b, nAw, nAb, nBw, nBb, p1w, p1b, p2w, p2b,
            preds, Psi, A, Mask, arow);
    }
}

// Round 17
// 251.433 us; speedup vs baseline: 1.0644x; 1.0644x over previous
//
#include <hip/hip_runtime.h>
#include <hip/hip_bf16.h>

// Problem constants
#define BB 8
#define SS 2048
#define DD 256
#define HH 512
#define LL 3
#define NROWS (BB * SS)

typedef float floatx4 __attribute__((ext_vector_type(4)));

// ---------------------------------------------------------------------------
// Launch 1: M[k][t] = sum_d pw[d][k]*pe[d][t]; c = pb . pe (verified R10)
// ---------------------------------------------------------------------------
__global__ void compute_M(const float* __restrict__ pw, const float* __restrict__ pb,
                          const float* __restrict__ pe, float* __restrict__ Mc)
{
    __shared__ float s0[4][256], s1[4][256];
    int tid = threadIdx.x;
    int k = tid & 255;
    int sub = tid >> 8;
    float a0 = 0.f, a1 = 0.f;
    #pragma unroll 8
    for (int d = sub * 64; d < sub * 64 + 64; ++d) {
        float w = pw[d * DD + k];
        a0 += w * pe[2 * d];
        a1 += w * pe[2 * d + 1];
    }
    s0[sub][k] = a0;
    s1[sub][k] = a1;
    __syncthreads();
    if (tid < 256) {
        Mc[2 * tid]     = s0[0][tid] + s0[1][tid] + s0[2][tid] + s0[3][tid];
        Mc[2 * tid + 1] = s1[0][tid] + s1[1][tid] + s1[2][tid] + s1[3][tid];
    }
    if (tid < 64) {
        float c0 = 0.f, c1 = 0.f;
        for (int d = tid; d < DD; d += 64) {
            c0 += pb[d] * pe[2 * d];
            c1 += pb[d] * pe[2 * d + 1];
        }
        #pragma unroll
        for (int dd = 32; dd; dd >>= 1) {
            c0 += __shfl_xor(c0, dd);
            c1 += __shfl_xor(c1, dd);
        }
        if (tid == 0) { Mc[512] = c0; Mc[513] = c1; }
    }
}

// ---------------------------------------------------------------------------
// Launch 2: psi (4-lane-group, verified R2/R15) + fused h0 (verified R15).
// 256 blocks x 256 threads; 64 rows/block.
// ---------------------------------------------------------------------------
__global__ void psi_kernel(const float* __restrict__ x, const float* __restrict__ Mc,
                           const float* __restrict__ hebb,
                           float* __restrict__ psi, float* __restrict__ T)
{
    __shared__ float sM[516];
    __shared__ float sH[2];
    int tid = threadIdx.x;
    for (int i = tid; i < 514; i += 256) sM[i] = Mc[i];
    __syncthreads();

    int sub = tid & 3;
    int rloc = tid >> 2;                    // 0..63
    int rid = blockIdx.x * 64 + rloc;
    const float4* xr = reinterpret_cast<const float4*>(x + (size_t)rid * DD);
    float a0 = 0.f, a1 = 0.f;
    #pragma unroll
    for (int i = sub; i < DD / 4; i += 4) {
        float4 v = xr[i];
        int k2 = i * 8;
        a0 += v.x * sM[k2]     + v.y * sM[k2 + 2] + v.z * sM[k2 + 4] + v.w * sM[k2 + 6];
        a1 += v.x * sM[k2 + 1] + v.y * sM[k2 + 3] + v.z * sM[k2 + 5] + v.w * sM[k2 + 7];
    }
    a0 += __shfl_xor(a0, 1); a0 += __shfl_xor(a0, 2);
    a1 += __shfl_xor(a1, 1); a1 += __shfl_xor(a1, 2);

    bool leader = (sub == 0);
    float px = 0.f, py = 0.f;
    if (leader) {
        a0 += sM[512];
        a1 += sM[513];
        float n = sqrtf(a0 * a0 + a1 * a1);
        float scale = 1.f / (n + 1e-8f);
        float r = n * scale;
        #pragma unroll
        for (int it = 0; it < 7; ++it) {
            float f = r / (r + 1e-8f);
            scale *= f;
            r *= f;
        }
        px = a0 * scale;
        py = a1 * scale;
        float2 pv;
        pv.x = px;
        pv.y = py;
        *reinterpret_cast<float2*>(psi + (size_t)rid * 2) = pv;
    }

    // h0: row b*SS + (SS-1) lives in blocks with (blockIdx & 31)==31, rloc==63
    if ((blockIdx.x & 31) == 31) {          // block-uniform branch
        if (leader && rloc == 63) { sH[0] = px; sH[1] = py; }
        __syncthreads();
        float hx = sH[0], hy = sH[1];
        int b = blockIdx.x >> 5;
        T[(size_t)b * HH + tid]       = hx * hebb[2 * tid]         + hy * hebb[2 * tid + 1];
        T[(size_t)b * HH + tid + 256] = hx * hebb[2 * (tid + 256)] + hy * hebb[2 * (tid + 256) + 1];
    }
}

// ---------------------------------------------------------------------------
// Tiny-batch GEMM stage (verified R10/R14/R15) — mm blocks ONLY (no stores).
// ---------------------------------------------------------------------------
__global__ void head_mm(const float* __restrict__ X, int K,
                        const float* __restrict__ xlnw, const float* __restrict__ xlnb,
                        const float* __restrict__ W, const float* __restrict__ bias,
                        const float* __restrict__ res,
                        const float* __restrict__ reslnw, const float* __restrict__ reslnb,
                        float* __restrict__ out, int J, int G, int act)
{
    const int bid = blockIdx.x;
    extern __shared__ float sX[];
    __shared__ float s_m[8], s_r[8], s_rm[8], s_rr[8];
    const int tid = threadIdx.x;
    const int row = tid >> 5, lane = tid & 31;
    const bool doLN = (xlnw != nullptr);
    const bool doRLN = (res != nullptr) && (reslnw != nullptr);

    if (doLN) {
        float s = 0.f, ss = 0.f;
        for (int k = lane; k < K; k += 32) {
            float v = X[row * K + k];
            s += v; ss += v * v;
        }
        for (int d = 16; d; d >>= 1) { s += __shfl_down(s, d); ss += __shfl_down(ss, d); }
        if (lane == 0) {
            float m = s / K;
            s_m[row] = m;
            s_r[row] = rsqrtf(ss / K - m * m + 1e-5f);
        }
    }
    if (doRLN) {
        float s = 0.f, ss = 0.f;
        for (int k = lane; k < J; k += 32) {
            float v = res[row * J + k];
            s += v; ss += v * v;
        }
        for (int d = 16; d; d >>= 1) { s += __shfl_down(s, d); ss += __shfl_down(ss, d); }
        if (lane == 0) {
            float m = s / J;
            s_rm[row] = m;
            s_rr[row] = rsqrtf(ss / J - m * m + 1e-5f);
        }
    }
    __syncthreads();

    if (doLN) {
        for (int idx = tid; idx < 8 * K; idx += 256) {
            int b = idx / K, k = idx - b * K;
            sX[idx] = (X[idx] - s_m[b]) * s_r[b] * xlnw[k] + xlnb[k];
        }
        __syncthreads();
    }

    const float* __restrict__ Xp = doLN ? (const float*)sX : X;
    const int g = tid & (G - 1);
    const int jj = tid / G;
    const int j = bid * (256 / G) + jj;

    float acc[8] = {0.f, 0.f, 0.f, 0.f, 0.f, 0.f, 0.f, 0.f};
    if (j < J) {
        const float4* W4 = reinterpret_cast<const float4*>(W + (size_t)j * K);
        const int K4 = K >> 2;
        for (int i4 = g; i4 < K4; i4 += G) {
            float4 w4 = W4[i4];
            int k = i4 << 2;
            #pragma unroll
            for (int b = 0; b < 8; ++b) {
                float4 xv = *reinterpret_cast<const float4*>(Xp + b * K + k);
                acc[b] = fmaf(w4.x, xv.x, acc[b]);
                acc[b] = fmaf(w4.y, xv.y, acc[b]);
                acc[b] = fmaf(w4.z, xv.z, acc[b]);
                acc[b] = fmaf(w4.w, xv.w, acc[b]);
            }
        }
    }
    for (int d = G >> 1; d; d >>= 1) {
        #pragma unroll
        for (int b = 0; b < 8; ++b) acc[b] += __shfl_down(acc[b], d);
    }
    if (g == 0 && j < J) {
        float bs = bias ? bias[j] : 0.f;
        #pragma unroll
        for (int b = 0; b < 8; ++b) {
            float v = acc[b] + bs;
            if (act) v = v / (1.f + expf(-v));   // silu
            if (res) {
                float rv = res[(size_t)b * J + j];
                if (reslnw) rv = (rv - s_rm[b]) * s_rr[b] * reslnw[j] + reslnb[j];
                v += rv;
            }
            out[(size_t)b * J + j] = v;
        }
    }
}

// ---------------------------------------------------------------------------
// Per-row LN for [8][N] in LDS (verified R13/R14). sh=log2(N). In-place safe.
// ---------------------------------------------------------------------------
__device__ __forceinline__ void ln8(const float* in, float* out, int N, int sh,
                                    const float* __restrict__ w,
                                    const float* __restrict__ bvec,
                                    float* s_m, float* s_r, int tid)
{
    int row = tid >> 5, lane = tid & 31;
    float s = 0.f, ss = 0.f;
    for (int k = lane; k < N; k += 32) {
        float v = in[(row << sh) + k];
        s += v; ss += v * v;
    }
    #pragma unroll
    for (int d = 16; d; d >>= 1) { s += __shfl_down(s, d); ss += __shfl_down(ss, d); }
    if (lane == 0) {
        float m = s / N;
        s_m[row] = m;
        s_r[row] = rsqrtf(ss / N - m * m + 1e-5f);
    }
    __syncthreads();
    for (int idx = tid; idx < (N << 3); idx += 256) {
        int b = idx >> sh, k = idx & (N - 1);
        out[idx] = (in[idx] - s_m[b]) * s_r[b] * w[k] + bvec[k];
    }
    __syncthreads();
}

// ---------------------------------------------------------------------------
// Tail (verified R14): single block — LN chain + p1/silu + LN(normB) + preds.
// ---------------------------------------------------------------------------
__global__ void tail_kernel(const float* __restrict__ T,
                            const float* __restrict__ ln2w, const float* __restrict__ ln2b,
                            const float* __restrict__ nAw, const float* __restrict__ nAb,
                            const float* __restrict__ nBw, const float* __restrict__ nBb,
                            const float* __restrict__ p1w, const float* __restrict__ p1b,
                            const float* __restrict__ p2w, const float* __restrict__ p2b,
                            float* __restrict__ preds)
{
    const int tid = threadIdx.x;
    __shared__ __align__(16) float sT[8 * HH];
    __shared__ __align__(16) float sX[8 * HH];
    __shared__ __align__(16) float sS[8 * 256];
    __shared__ float s_m[8], s_r[8];
    const float4* sX4 = reinterpret_cast<const float4*>(sX);

    for (int idx = tid; idx < 4096; idx += 256) sT[idx] = T[idx];
    __syncthreads();
    ln8(sT, sX, HH, 9, ln2w + 2 * HH, ln2b + 2 * HH, s_m, s_r, tid);
    ln8(sX, sX, HH, 9, nAw, nAb, s_m, s_r, tid);
    {
        int j = tid;
        float acc[8] = {0,0,0,0,0,0,0,0};
        const float4* W4 = reinterpret_cast<const float4*>(p1w + (size_t)j * HH);
        for (int i4 = 0; i4 < 128; ++i4) {
            float4 w = W4[i4];
            #pragma unroll
            for (int b = 0; b < 8; ++b) {
                float4 xv = sX4[b * 128 + i4];
                acc[b] = fmaf(w.x, xv.x, acc[b]);
                acc[b] = fmaf(w.y, xv.y, acc[b]);
                acc[b] = fmaf(w.z, xv.z, acc[b]);
                acc[b] = fmaf(w.w, xv.w, acc[b]);
            }
        }
        float bp = p1b[j];
        #pragma unroll
        for (int b = 0; b < 8; ++b) {
            float v = acc[b] + bp;
            v = v / (1.f + expf(-v));
            sS[b * 256 + j] = v;
        }
    }
    __syncthreads();
    ln8(sS, sS, 256, 8, nBw, nBb, s_m, s_r, tid);
    {
        int b = tid >> 5, k = tid & 31;
        float s = 0.f;
        for (int kk = k; kk < 256; kk += 32) s += sS[b * 256 + kk] * p2w[kk];
        #pragma unroll
        for (int d = 16; d; d >>= 1) s += __shfl_down(s, d);
        if (k == 0) preds[b] = s + p2b[0];
    }
}

// ---------------------------------------------------------------------------
// Final launch: ALL A/mask rows, plain cached float4 stores at full write BW.
// Nothing runs after this kernel, so dirty L2 is free. 4096 blocks x 4 rows.
// ---------------------------------------------------------------------------
__global__ void amask_all(const float* __restrict__ psi,
                          float* __restrict__ A, float* __restrict__ M)
{
    int tid = threadIdx.x;
    int r0 = blockIdx.x * 4;
    #pragma unroll
    for (int rr = 0; rr < 4; ++rr) {
        int blk = r0 + rr;
        int b = blk >> 11, i = blk & (SS - 1);
        float2 pi = *reinterpret_cast<const float2*>(psi + (size_t)blk * 2);
        #pragma unroll
        for (int c = 0; c < 2; ++c) {
            int j0 = c * 1024 + tid * 4;
            const float4* pr = reinterpret_cast<const float4*>(psi + ((size_t)b * SS + j0) * 2);
            float4 q0 = pr[0], q1 = pr[1];
            float4 o;
            o.x = pi.x * q0.x + pi.y * q0.y;
            o.y = pi.x * q0.z + pi.y * q0.w;
            o.z = pi.x * q1.x + pi.y * q1.y;
            o.w = pi.x * q1.z + pi.y * q1.w;
            size_t rb = (size_t)blk * SS + j0;
            *reinterpret_cast<float4*>(A + rb) = o;
            float4 m;
            m.x = (i == j0    ) ? 1.f : 0.f;
            m.y = (i == j0 + 1) ? 1.f : 0.f;
            m.z = (i == j0 + 2) ? 1.f : 0.f;
            m.w = (i == j0 + 3) ? 1.f : 0.f;
            *reinterpret_cast<float4*>(M + rb) = m;
        }
    }
}

// ---------------------------------------------------------------------------
extern "C" void kernel_launch(void* const* d_in, const int* in_sizes, int n_in,
                              void* d_out, int out_size, void* d_ws, size_t ws_size,
                              hipStream_t stream)
{
    const float* x      = (const float*)d_in[0];
    const float* proj_w = (const float*)d_in[1];
    const float* proj_b = (const float*)d_in[2];
    const float* pe     = (const float*)d_in[3];
    const float* hebb   = (const float*)d_in[4];
    const float* ai_w   = (const float*)d_in[5];
    const float* ai_b   = (const float*)d_in[6];
    const float* ao_w   = (const float*)d_in[7];
    const float* ao_b   = (const float*)d_in[8];
    const float* f1_w   = (const float*)d_in[9];
    const float* f1_b   = (const float*)d_in[10];
    const float* f2_w   = (const float*)d_in[11];
    const float* f2_b   = (const float*)d_in[12];
    const float* ln1w   = (const float*)d_in[13];
    const float* ln1b   = (const float*)d_in[14];
    const float* ln2w   = (const float*)d_in[15];
    const float* ln2b   = (const float*)d_in[16];
    const float* nAw    = (const float*)d_in[17];
    const float* nAb    = (const float*)d_in[18];
    const float* nBw    = (const float*)d_in[19];
    const float* nBb    = (const float*)d_in[20];
    const float* p1w    = (const float*)d_in[21];
    const float* p1b    = (const float*)d_in[22];
    const float* p2w    = (const float*)d_in[23];
    const float* p2b    = (const float*)d_in[24];

    float* out   = (float*)d_out;
    // output layout: preds(8) | A(B*S*S) | mask(B*S*S) | psi(B*S*2)
    float* preds = out;
    float* A     = out + 8;
    float* Mask  = out + 8 + (size_t)BB * SS * SS;
    float* Psi   = out + 8 + (size_t)2 * BB * SS * SS;

    float* ws = (float*)d_ws;
    float* Mc = ws;            // 514
    float* T  = ws + 640;      // 8x512
    float* V  = ws + 4736;     // 8x512
    float* T1 = ws + 8832;     // 8x512
    float* F  = ws + 12928;    // 8x2048

    // ---- 1: Mc ----
    compute_M<<<1, 1024, 0, stream>>>(proj_w, proj_b, pe, Mc);
    // ---- 2: psi + h0 ----
    psi_kernel<<<NROWS / 64, 256, 0, stream>>>(x, Mc, hebb, Psi, T);

    // ---- 3..14: 12 mm-only stages ----
    for (int l = 0; l < LL; ++l) {
        const float* pxw = l ? ln2w + (l - 1) * HH : nullptr;
        const float* pxb = l ? ln2b + (l - 1) * HH : nullptr;
        // v = LN?(T) @ Wv^T + bv            (J=512, K=512, G=32)
        head_mm<<<64, 256, (pxw ? 8 * HH * 4 : 0), stream>>>(
            T, HH, pxw, pxb,
            ai_w + ((size_t)l * 3 * HH + 2 * HH) * HH, ai_b + l * 3 * HH + 2 * HH,
            nullptr, nullptr, nullptr, V, HH, 32, 0);
        // t1 = resLN?(T) + (v @ Wo^T + bo)  (J=512, K=512)
        head_mm<<<64, 256, 0, stream>>>(
            V, HH, nullptr, nullptr,
            ao_w + (size_t)l * HH * HH, ao_b + l * HH,
            T, pxw, pxb, T1, HH, 32, 0);
        // f = silu(LN(t1,ln1) @ W1^T + b1)  (J=2048, K=512, G=16)
        head_mm<<<128, 256, 8 * HH * 4, stream>>>(
            T1, HH, ln1w + l * HH, ln1b + l * HH,
            f1_w + (size_t)l * 4 * HH * HH, f1_b + l * 4 * HH,
            nullptr, nullptr, nullptr, F, 4 * HH, 16, 1);
        // t2 = LN(t1,ln1) + (f @ W2^T + b2) (J=512, K=2048, G=64)
        head_mm<<<128, 256, 0, stream>>>(
            F, 4 * HH, nullptr, nullptr,
            f2_w + (size_t)l * HH * 4 * HH, f2_b + l * HH,
            T1, ln1w + l * HH, ln1b + l * HH, T, HH, 64, 0);
    }
    // ---- 15: tail ----
    tail_kernel<<<1, 256, 0, stream>>>(
        T, ln2w, ln2b, nAw, nAb, nBw, nBb, p1w, p1b, p2w, p2b, preds);
    // ---- 16: all A/mask stores, plain cached writes, full BW ----
    amask_all<<<NROWS / 4, 256, 0, stream>>>(Psi, A, Mask);
}